// Round 9
// baseline (5024.273 us; speedup 1.0000x reference)
//
#include <hip/hip_runtime.h>

typedef unsigned int u32;
typedef _Float16 f16x2 __attribute__((ext_vector_type(2)));

#define TP 600
#define TQ 60
#define BB 64
#define EMB 344
#define HH 256
#define H2 128
#define GG 512

// ---------- fast math helpers ----------
__device__ __forceinline__ float exp2_fast(float x){
#if __has_builtin(__builtin_amdgcn_exp2f)
    return __builtin_amdgcn_exp2f(x);
#else
    return exp2f(x);
#endif
}
__device__ __forceinline__ float rcp_fast(float x){
#if __has_builtin(__builtin_amdgcn_rcpf)
    return __builtin_amdgcn_rcpf(x);
#else
    return 1.0f / x;
#endif
}
__device__ __forceinline__ float sigm_fast(float x){
    return rcp_fast(1.f + exp2_fast(-1.44269504f * x));
}
__device__ __forceinline__ float tanh_fast(float x){
    return 1.f - 2.f * rcp_fast(1.f + exp2_fast(2.88539008f * x));
}
__device__ __forceinline__ float dot2x(u32 w, u32 h, float acc){
    f16x2 wv = __builtin_bit_cast(f16x2, w);
    f16x2 hv = __builtin_bit_cast(f16x2, h);
    acc = fmaf((float)wv.x, (float)hv.x, acc);
    acc = fmaf((float)wv.y, (float)hv.y, acc);
    return acc;
}
// v_dot2_f32_f16: 2 fp16 MACs, fp32 accumulate, ONE instruction
__device__ __forceinline__ float dot2f(u32 w, u32 h, float acc){
#if __has_builtin(__builtin_amdgcn_fdot2)
    return __builtin_amdgcn_fdot2(__builtin_bit_cast(f16x2, w),
                                  __builtin_bit_cast(f16x2, h), acc, false);
#else
    return dot2x(w, h, acc);
#endif
}
__device__ __forceinline__ u32 pack2(float a, float b){
    f16x2 v; v.x = (_Float16)a; v.y = (_Float16)b;
    return __builtin_bit_cast(u32, v);
}
// readlane: lane index MUST be wave-uniform (constant in all uses below!)
__device__ __forceinline__ u32 lane_bcast(u32 v, int l){
    return (u32)__builtin_amdgcn_readlane((int)v, l);
}
// LDS-only barrier: does NOT drain vmcnt -> global prefetches/stores stay in
// flight across it; vmcnt waits land at use, ~a step later.
__device__ __forceinline__ void bar_lds(){
    asm volatile("s_waitcnt lgkmcnt(0)\n\ts_barrier" ::: "memory");
}

// ---------- shared subroutines for the match kernel ----------
__device__ __forceinline__ void attn_p2(int tq2, int sub, const u32* aqr,
                                        const float* sumt_s, const float* wa_s,
                                        _Float16* e16)
{
    float p0 = 0.f, p1 = 0.f;
    #pragma unroll
    for (int i = 0; i < 8; ++i) {
        f16x2 av = __builtin_bit_cast(f16x2, aqr[i]);
        float2 st = *(const float2*)&sumt_s[16*sub + 2*i];
        float2 wv = *(const float2*)&wa_s[16*sub + 2*i];
        p0 = fmaf(wv.x, tanh_fast((float)av.x + st.x), p0);
        p1 = fmaf(wv.y, tanh_fast((float)av.y + st.y), p1);
    }
    float part = p0 + p1;
    part += __shfl_xor(part, 1);
    part += __shfl_xor(part, 2);
    part += __shfl_xor(part, 4);
    part += __shfl_xor(part, 8);
    if (sub == 0 && tq2 < 60) {
        float sc = fminf(9.f, fmaxf(-9.f, part));
        e16[tq2] = (_Float16)exp2_fast(sc * 1.44269504f);
    }
}
__device__ __forceinline__ void cell4(const float* gates, int l, float m,
                                      float& c0, float& c1, u32& hp,
                                      float& h0o, float& h1o)
{
    float2 gi2 = *(const float2*)&gates[      2*l];
    float2 gf2 = *(const float2*)&gates[128 + 2*l];
    float2 gg2 = *(const float2*)&gates[256 + 2*l];
    float2 go2 = *(const float2*)&gates[384 + 2*l];
    c0 = gf2.x*c0 + gi2.x*gg2.x;
    c1 = gf2.y*c1 + gi2.y*gg2.y;
    float h0 = go2.x * tanh_fast(c0);
    float h1 = go2.y * tanh_fast(c1);
    h0 *= m; h1 *= m; c0 *= m; c1 *= m;
    hp = pack2(h0, h1);
    h0o = h0; h1o = h1;
}

// ---------- prep: transpose weights (fp32 WT4 layout) + fp16 packing ----------
__global__ void prep_kernel(const float* __restrict__ pre0_Wih, const float* __restrict__ pre0_Whh,
                            const float* __restrict__ pre1_Wih, const float* __restrict__ pre1_Whh,
                            const float* __restrict__ Wq, const float* __restrict__ Wp,
                            const float* __restrict__ Whm,
                            const float* __restrict__ Whhm,
                            float* __restrict__ WT0, float* __restrict__ WT1,
                            float* __restrict__ WTq, float* __restrict__ WTp,
                            float* __restrict__ WTz, const float* __restrict__ Wihm,
                            u32* __restrict__ P0hh, u32* __restrict__ P1hh,
                            u32* __restrict__ PMhh, u32* __restrict__ PMwh)
{
    int g = blockIdx.x * blockDim.x + threadIdx.x;
    int gs = gridDim.x * blockDim.x;
    for (int idx = g; idx < 512*344; idx += gs) {
        int j = idx / 344, k = idx - j*344;
        WT0[((k>>2)*512 + j)*4 + (k&3)] = pre0_Wih[idx];
    }
    for (int idx = g; idx < 512*256; idx += gs) {
        int j = idx >> 8, k = idx & 255;
        WT1[((k>>2)*512 + j)*4 + (k&3)] = pre1_Wih[idx];
    }
    for (int idx = g; idx < 256*256; idx += gs) {
        int j = idx >> 8, k = idx & 255;
        WTq[((k>>2)*256 + j)*4 + (k&3)] = Wq[idx];
        WTp[((k>>2)*256 + j)*4 + (k&3)] = Wp[idx];
    }
    for (int idx = g; idx < 512*256; idx += gs) {
        int j = idx >> 8, k = idx & 255;
        WTz[((k>>2)*512 + j)*4 + (k&3)] = Wihm[j*512 + k];
    }
    for (int idx = g; idx < 64*512; idx += gs) {
        int k2 = idx >> 9, j = idx & 511;
        P0hh[idx] = pack2(pre0_Whh[j*128 + 2*k2], pre0_Whh[j*128 + 2*k2 + 1]);
        P1hh[idx] = pack2(pre1_Whh[j*128 + 2*k2], pre1_Whh[j*128 + 2*k2 + 1]);
        PMhh[idx] = pack2(Whhm[j*128 + 2*k2], Whhm[j*128 + 2*k2 + 1]);
    }
    for (int idx = g; idx < 64*256; idx += gs) {
        int k2 = idx >> 8, j = idx & 255;
        PMwh[idx] = pack2(Whm[j*128 + 2*k2], Whm[j*128 + 2*k2 + 1]);
    }
}

// ---------- batched projection ----------
template<int K, int M>
__global__ __launch_bounds__(M)
void proj_kernel(const float* __restrict__ X0, const float* __restrict__ W0,
                 const float* __restrict__ b0, float* __restrict__ C0, int T0,
                 const float* __restrict__ X1, const float* __restrict__ W1,
                 const float* __restrict__ b1, float* __restrict__ C1)
{
    __shared__ float Xs[K*68];
    int t = blockIdx.x;
    const float* X; const float* W; const float* bias; float* C; int trow;
    if (t < T0) { X = X0; W = W0; bias = b0; C = C0; trow = t; }
    else        { X = X1; W = W1; bias = b1; C = C1; trow = t - T0; }
    int j = threadIdx.x;
    for (int b = 0; b < 64; ++b) {
        for (int k = j; k < K; k += M)
            Xs[k*68 + b] = X[(trow*64 + b)*K + k];
    }
    __syncthreads();
    float acc[64];
    float binit = bias ? bias[j] : 0.f;
    #pragma unroll
    for (int b = 0; b < 64; ++b) acc[b] = binit;
    const float4* W4 = (const float4*)W;
    for (int k4 = 0; k4 < K/4; ++k4) {
        float4 w4 = W4[k4*M + j];
        float wv[4] = {w4.x, w4.y, w4.z, w4.w};
        #pragma unroll
        for (int kk = 0; kk < 4; ++kk) {
            int k = 4*k4 + kk;
            #pragma unroll
            for (int b4 = 0; b4 < 16; ++b4) {
                float4 x4 = *((const float4*)&Xs[k*68 + 4*b4]);
                acc[4*b4+0] = fmaf(wv[kk], x4.x, acc[4*b4+0]);
                acc[4*b4+1] = fmaf(wv[kk], x4.y, acc[4*b4+1]);
                acc[4*b4+2] = fmaf(wv[kk], x4.z, acc[4*b4+2]);
                acc[4*b4+3] = fmaf(wv[kk], x4.w, acc[4*b4+3]);
            }
        }
    }
    for (int b = 0; b < 64; ++b)
        C[(trow*64 + b)*M + j] = acc[b];
}

// ---------- Yq precompute ----------
__global__ __launch_bounds__(512)
void yq_kernel(const float* __restrict__ Hq1, const float* __restrict__ Wihm,
               float* __restrict__ Yq)
{
    __shared__ float Xs[256*68];
    int tq = blockIdx.x;
    int j = threadIdx.x;
    for (int b = 0; b < 64; ++b) {
        for (int k = j; k < 256; k += 512)
            Xs[k*68 + b] = Hq1[(tq*64 + b)*256 + k];
    }
    __syncthreads();
    float acc[64];
    #pragma unroll
    for (int b = 0; b < 64; ++b) acc[b] = 0.f;
    const float4* W4 = (const float4*)(Wihm + j*512 + 256);
    for (int k4 = 0; k4 < 64; ++k4) {
        float4 w4 = W4[k4];
        float wv[4] = {w4.x, w4.y, w4.z, w4.w};
        #pragma unroll
        for (int kk = 0; kk < 4; ++kk) {
            int k = 4*k4 + kk;
            #pragma unroll
            for (int b4 = 0; b4 < 16; ++b4) {
                float4 x4 = *((const float4*)&Xs[k*68 + 4*b4]);
                acc[4*b4+0] = fmaf(wv[kk], x4.x, acc[4*b4+0]);
                acc[4*b4+1] = fmaf(wv[kk], x4.y, acc[4*b4+1]);
                acc[4*b4+2] = fmaf(wv[kk], x4.z, acc[4*b4+2]);
                acc[4*b4+3] = fmaf(wv[kk], x4.w, acc[4*b4+3]);
            }
        }
    }
    for (int b = 0; b < 64; ++b)
        Yq[(tq*64 + b)*512 + j] = acc[b];
}

// ---------- pre-BiLSTM recurrence (h discarded; c masked; h = tanh(c)) ----------
// 768 threads = 12 waves (3/SIMD). WAVE-uniform k-split (readlane indices are
// literal constants): waves 0-5 own gate j (k-pairs 0..31 + combine + nonlin);
// waves 6-11 compute k-pairs 32..63 partial -> LDS. 2 bar_lds/step.
// Cell computed redundantly per lane; h pair lives in a register.
__global__ __launch_bounds__(768)
void rec_pre_kernel(const float* __restrict__ Xp, const float* __restrict__ Xq,
                    const u32* __restrict__ Whh,
                    const float* __restrict__ mask_p, const float* __restrict__ mask_q,
                    float* __restrict__ Hp, float* __restrict__ Hq)
{
    int bid = blockIdx.x;
    int sb2 = bid & 127; int b = sb2 >> 1; int dir = sb2 & 1;
    const float* X; const float* mask; float* Hout; int T;
    if (bid < 128) { X = Xp; mask = mask_p; Hout = Hp; T = TP; }
    else           { X = Xq; mask = mask_q; Hout = Hq; T = TQ; }
    int t = threadIdx.x;          // 0..767
    int l = t & 63;
    __shared__ float gates[384];
    __shared__ float partG[384];
    u32 hp = 0u;
    float c0 = 0.f, c1 = 0.f;
    int t0 = dir ? (T-1) : 0;
    int t1i = (T > 1) ? (dir ? (T-2) : 1) : t0;
    float m_c = mask[t0*64 + b];
    float m_1 = mask[t1i*64 + b];

    if (t < 384) {
        // ===== owners: k-pairs 0..31 =====
        int j = t;
        u32 w[32];
        #pragma unroll
        for (int q = 0; q < 32; ++q) w[q] = Whh[q*512 + j];
        float x_c = X[(t0*64 + b)*512 + j];
        float x_1 = X[(t1i*64 + b)*512 + j];
        float hd0, hd1;
        for (int s = 0; s < T; ++s) {
            int ti = dir ? (T-1-s) : s;
            int s2 = (s+2 < T) ? (s+2) : (T-1);
            int t2 = dir ? (T-1-s2) : s2;
            float x_2 = X[(t2*64 + b)*512 + j];   // depth-2 prefetch
            float m_2 = mask[t2*64 + b];
            float a0 = 0.f, a1 = 0.f;
            #pragma unroll
            for (int q = 0; q < 32; q += 2) {
                a0 = dot2f(w[q],   lane_bcast(hp, q),   a0);
                a1 = dot2f(w[q+1], lane_bcast(hp, q+1), a1);
            }
            bar_lds();                            // barP (partner partial ready)
            float g = x_c + (a0 + a1) + partG[j];
            gates[j] = ((j >> 7) == 2) ? tanh_fast(g) : sigm_fast(g);
            bar_lds();                            // barG (gates ready)
            // CELL (pre-layer quirk): c masked, h = tanh(c)
            {
                float2 gi2 = *(const float2*)&gates[      2*l];
                float2 gf2 = *(const float2*)&gates[128 + 2*l];
                float2 gg2 = *(const float2*)&gates[256 + 2*l];
                c0 = gf2.x*c0 + gi2.x*gg2.x;  c0 *= m_c;
                c1 = gf2.y*c1 + gi2.y*gg2.y;  c1 *= m_c;
                hd0 = tanh_fast(c0); hd1 = tanh_fast(c1);
                hp = pack2(hd0, hd1);
                if (t < 64) {
                    float2 hv; hv.x = hd0; hv.y = hd1;
                    *(float2*)&Hout[(ti*64 + b)*256 + dir*128 + 2*l] = hv;
                }
            }
            x_c = x_1; x_1 = x_2; m_c = m_1; m_1 = m_2;
        }
    } else {
        // ===== partners: k-pairs 32..63 =====
        int j = t - 384;
        u32 w[32];
        #pragma unroll
        for (int q = 0; q < 32; ++q) w[q] = Whh[(32 + q)*512 + j];
        for (int s = 0; s < T; ++s) {
            int s2 = (s+2 < T) ? (s+2) : (T-1);
            int t2 = dir ? (T-1-s2) : s2;
            float m_2 = mask[t2*64 + b];
            float a0 = 0.f, a1 = 0.f;
            #pragma unroll
            for (int q = 0; q < 32; q += 2) {
                a0 = dot2f(w[q],   lane_bcast(hp, 32 + q),     a0);
                a1 = dot2f(w[q+1], lane_bcast(hp, 32 + q + 1), a1);
            }
            partG[j] = a0 + a1;
            bar_lds();                            // barP
            bar_lds();                            // barG
            {
                float2 gi2 = *(const float2*)&gates[      2*l];
                float2 gf2 = *(const float2*)&gates[128 + 2*l];
                float2 gg2 = *(const float2*)&gates[256 + 2*l];
                c0 = gf2.x*c0 + gi2.x*gg2.x;  c0 *= m_c;
                c1 = gf2.y*c1 + gi2.y*gg2.y;  c1 *= m_c;
                hp = pack2(tanh_fast(c0), tanh_fast(c1));
            }
            m_c = m_1; m_1 = m_2;
        }
    }
}

// ---------- Match-LSTM recurrence: one block per (b, dir), 1024 threads ----------
// 16 waves (4/SIMD; block residency forces VGPR<=128 -> the two wave-sets run
// SEPARATE loop bodies so whh[] and wh[] overlap in the register file).
// Waves 0-7 (t<512): gate owners -- full h@Whh (readlane 0..63), y/S over
//   tq-pairs 0..15, combine + gate nonlinearity.
// Waves 8-11: full sumt = ap + h@Wh -> LDS. Waves 8-15: y/S partial over
//   tq-pairs 16..31 -> LDS. All readlane indices are literal constants.
// 4 bar_lds/step; cell redundant per lane (h pair in a register).
__global__ __launch_bounds__(1024)
void match_kernel(const float* __restrict__ ap,   // [600][64][256]
                  const float* __restrict__ aqg,  // [60][64][256]
                  const float* __restrict__ Zp,   // [600][64][512]
                  const float* __restrict__ Yq,   // [60][64][512]
                  const float* __restrict__ Wa,   // [256]
                  const float* __restrict__ mask_p,
                  const u32* __restrict__ PMwh,   // [64][256] packed Wh
                  const u32* __restrict__ PMhh,   // [64][512] packed Whh
                  float* __restrict__ out)        // [600][64][256]
{
    int bid = blockIdx.x; int b = bid >> 1; int dir = bid & 1;
    int t = threadIdx.x;                          // 0..1023
    int l = t & 63;
    int jj = t & 511;
    int tq2 = t >> 4, sub = t & 15;
    __shared__ __align__(16) float sumt_s[256];
    __shared__ __align__(16) float wa_s[256];
    __shared__ __align__(16) float gates[512];
    __shared__ __align__(16) float partY[512];
    __shared__ __align__(16) float partS[512];
    __shared__ __align__(16) _Float16 e16[64];

    // ---- common staging ----
    u32 aqr[8];
    if (tq2 < 60) {
        #pragma unroll
        for (int i = 0; i < 8; ++i) {
            float2 a = *(const float2*)&aqg[(tq2*64 + b)*256 + 16*sub + 2*i];
            aqr[i] = pack2(a.x, a.y);
        }
    } else {
        #pragma unroll
        for (int i = 0; i < 8; ++i) aqr[i] = 0u;
    }
    u32 Yqr[16];                                  // tq-pairs (t<512 ? 0..15 : 16..31)
    {
        int pairbase = (t >> 9) * 16;
        #pragma unroll
        for (int i = 0; i < 16; ++i) {
            int pr = pairbase + i;
            int ta = 2*pr, tb = 2*pr + 1;
            float ya = (ta < 60) ? Yq[(ta*64 + b)*512 + jj] : 0.f;
            float yb = (tb < 60) ? Yq[(tb*64 + b)*512 + jj] : 0.f;
            Yqr[i] = pack2(ya, yb);
        }
    }
    if (t < 256) wa_s[t] = Wa[t];
    if (t < 64)  e16[t] = (_Float16)0.f;          // tq 60..63 stay 0 forever
    u32 hp = 0u;
    float c0 = 0.f, c1 = 0.f;
    int ti0 = dir ? (TP-1) : 0;
    float m_c = mask_p[ti0*64 + b];
    const u32 ONE2 = 0x3C003C00u;                 // fp16 (1.0, 1.0)
    bar_lds();                                    // staging ready (both sets)

    if (t < 512) {
        // ===================== branch A: gate owners =====================
        u32 whh[64];
        #pragma unroll
        for (int q = 0; q < 64; ++q) whh[q] = PMhh[q*512 + jj];
        float zp_c = Zp[(ti0*64 + b)*512 + jj];
        float h_out0 = 0.f, h_out1 = 0.f; int ti_prev = 0;
        for (int s = 0; s < TP; ++s) {
            int ti = dir ? (TP-1-s) : s;
            int s1 = (s+1 < TP) ? (s+1) : s;
            int tn = dir ? (TP-1-s1) : s1;
            // P1: hwhh = h @ Whh[jj] (full, readlane 0..63)
            float w0 = 0.f, w1 = 0.f, w2 = 0.f, w3 = 0.f;
            #pragma unroll
            for (int q = 0; q < 64; q += 4) {
                w0 = dot2f(whh[q],   lane_bcast(hp, q),   w0);
                w1 = dot2f(whh[q+1], lane_bcast(hp, q+1), w1);
                w2 = dot2f(whh[q+2], lane_bcast(hp, q+2), w2);
                w3 = dot2f(whh[q+3], lane_bcast(hp, q+3), w3);
            }
            float hwhh = (w0 + w1) + (w2 + w3);
            bar_lds();                            // bar1 (sumt ready)
            if (s && t < 64) {
                float2 hv; hv.x = h_out0; hv.y = h_out1;
                *(float2*)&out[(ti_prev*64 + b)*256 + dir*128 + 2*l] = hv;
            }
            float zp_n = Zp[(tn*64 + b)*512 + jj];
            float m_n  = mask_p[tn*64 + b];
            attn_p2(tq2, sub, aqr, sumt_s, wa_s, e16);
            bar_lds();                            // bar2 (e ready)
            // P4a: own tq-pairs 0..15
            float y0 = 0.f, y1 = 0.f, S0 = 0.f, S1 = 0.f;
            {
                u32 ep = ((const u32*)e16)[l & 31];
                #pragma unroll
                for (int r4 = 0; r4 < 4; ++r4) {
                    u32 e0 = lane_bcast(ep, 4*r4+0), e1 = lane_bcast(ep, 4*r4+1);
                    u32 e2 = lane_bcast(ep, 4*r4+2), e3 = lane_bcast(ep, 4*r4+3);
                    y0 = dot2f(Yqr[4*r4+0], e0, y0); S0 = dot2f(ONE2, e0, S0);
                    y1 = dot2f(Yqr[4*r4+1], e1, y1); S1 = dot2f(ONE2, e1, S1);
                    y0 = dot2f(Yqr[4*r4+2], e2, y0); S0 = dot2f(ONE2, e2, S0);
                    y1 = dot2f(Yqr[4*r4+3], e3, y1); S1 = dot2f(ONE2, e3, S1);
                }
            }
            bar_lds();                            // bar2b (partner partials ready)
            {
                float Sf = (S0 + S1) + partS[jj];
                float yf = (y0 + y1) + partY[jj];
                float rn = rcp_fast(Sf);
                float g = zp_c + rn * yf + hwhh;
                gates[jj] = ((jj >> 7) == 2) ? tanh_fast(g) : sigm_fast(g);
            }
            bar_lds();                            // bar3 (gates ready)
            cell4(gates, l, m_c, c0, c1, hp, h_out0, h_out1);
            ti_prev = ti;
            zp_c = zp_n; m_c = m_n;
        }
        if (t < 64) {
            float2 hv; hv.x = h_out0; hv.y = h_out1;
            *(float2*)&out[(ti_prev*64 + b)*256 + dir*128 + 2*l] = hv;
        }
    } else {
        // ===================== branch B: helpers =====================
        bool hasS = (t < 768);                    // waves 8..11 (jj 0..255)
        u32 wh[64];
        if (hasS) {
            #pragma unroll
            for (int q = 0; q < 64; ++q) wh[q] = PMwh[q*256 + jj];
        }
        float ap_c = hasS ? ap[(ti0*64 + b)*256 + jj] : 0.f;
        float hd0, hd1;
        for (int s = 0; s < TP; ++s) {
            int s1 = (s+1 < TP) ? (s+1) : s;
            int tn = dir ? (TP-1-s1) : s1;
            // P1: sumt = ap + h @ Wh[jj] (full, readlane 0..63)
            if (hasS) {
                float s0 = ap_c, s1a = 0.f, s2 = 0.f, s3 = 0.f;
                #pragma unroll
                for (int q = 0; q < 64; q += 4) {
                    s0  = dot2f(wh[q],   lane_bcast(hp, q),   s0);
                    s1a = dot2f(wh[q+1], lane_bcast(hp, q+1), s1a);
                    s2  = dot2f(wh[q+2], lane_bcast(hp, q+2), s2);
                    s3  = dot2f(wh[q+3], lane_bcast(hp, q+3), s3);
                }
                sumt_s[jj] = (s0 + s1a) + (s2 + s3);
            }
            bar_lds();                            // bar1
            float ap_n = hasS ? ap[(tn*64 + b)*256 + jj] : 0.f;
            float m_n  = mask_p[tn*64 + b];
            attn_p2(tq2, sub, aqr, sumt_s, wa_s, e16);
            bar_lds();                            // bar2
            // P4b: tq-pairs 16..31 partial -> LDS
            {
                u32 ep = ((const u32*)e16)[l & 31];
                float y0 = 0.f, y1 = 0.f, S0 = 0.f, S1 = 0.f;
                #pragma unroll
                for (int r4 = 0; r4 < 4; ++r4) {
                    u32 e0 = lane_bcast(ep, 16+4*r4+0), e1 = lane_bcast(ep, 16+4*r4+1);
                    u32 e2 = lane_bcast(ep, 16+4*r4+2), e3 = lane_bcast(ep, 16+4*r4+3);
                    y0 = dot2f(Yqr[4*r4+0], e0, y0); S0 = dot2f(ONE2, e0, S0);
                    y1 = dot2f(Yqr[4*r4+1], e1, y1); S1 = dot2f(ONE2, e1, S1);
                    y0 = dot2f(Yqr[4*r4+2], e2, y0); S0 = dot2f(ONE2, e2, S0);
                    y1 = dot2f(Yqr[4*r4+3], e3, y1); S1 = dot2f(ONE2, e3, S1);
                }
                partY[jj] = y0 + y1;
                partS[jj] = S0 + S1;
            }
            bar_lds();                            // bar2b
            bar_lds();                            // bar3
            cell4(gates, l, m_c, c0, c1, hp, hd0, hd1);
            ap_c = ap_n; m_c = m_n;
        }
    }
}

// ---------- workspace layout (floats) ----------
#define O_BUFX   0UL          // 19,660,800  Xp0 -> Xp1 -> Zp
#define O_BUFXQ  19660800UL   //  1,966,080  Xq0 -> Xq1 -> Yq
#define O_HP0    21626880UL   //  9,830,400  Hp0 -> ap
#define O_HQ0    31457280UL   //    983,040  Hq0 -> aq
#define O_HP1    32440320UL   //  9,830,400
#define O_HQ1    42270720UL   //    983,040
#define O_WT0    43253760UL   //    176,128
#define O_WT1    43429888UL   //    131,072
#define O_WTQ    43560960UL   //     65,536
#define O_WTP    43626496UL   //     65,536
#define O_WTZ    43692032UL   //    131,072
#define O_P0HH   43823104UL   //     32,768 u32
#define O_P1HH   43855872UL
#define O_PMHH   43888640UL
#define O_PMWH   43921408UL   //     16,384 u32

extern "C" void kernel_launch(void* const* d_in, const int* in_sizes, int n_in,
                              void* d_out, int out_size, void* d_ws, size_t ws_size,
                              hipStream_t stream)
{
    const float* passage  = (const float*)d_in[0];
    const float* question = (const float*)d_in[1];
    const float* mask_p   = (const float*)d_in[2];
    const float* mask_q   = (const float*)d_in[3];
    const float* pre0_Wih = (const float*)d_in[4];
    const float* pre0_Whh = (const float*)d_in[5];
    const float* pre0_b   = (const float*)d_in[6];
    const float* pre1_Wih = (const float*)d_in[7];
    const float* pre1_Whh = (const float*)d_in[8];
    const float* pre1_b   = (const float*)d_in[9];
    const float* mq_Wq    = (const float*)d_in[10];
    const float* mq_Wp    = (const float*)d_in[11];
    const float* mq_bp    = (const float*)d_in[12];
    const float* mq_Wh    = (const float*)d_in[13];
    const float* mq_Wa    = (const float*)d_in[14];
    // d_in[15] = mq_ba: softmax-invariant, skipped
    const float* mq_Wih   = (const float*)d_in[16];
    const float* mq_Whh   = (const float*)d_in[17];
    const float* mq_b     = (const float*)d_in[18];

    float* ws = (float*)d_ws;
    float* bufX  = ws + O_BUFX;
    float* bufXq = ws + O_BUFXQ;
    float* Hp0   = ws + O_HP0;
    float* Hq0   = ws + O_HQ0;
    float* Hp1   = ws + O_HP1;
    float* Hq1   = ws + O_HQ1;
    float* WT0   = ws + O_WT0;
    float* WT1   = ws + O_WT1;
    float* WTq   = ws + O_WTQ;
    float* WTp   = ws + O_WTP;
    float* WTz   = ws + O_WTZ;
    u32*   P0hh  = (u32*)(ws + O_P0HH);
    u32*   P1hh  = (u32*)(ws + O_P1HH);
    u32*   PMhh  = (u32*)(ws + O_PMHH);
    u32*   PMwh  = (u32*)(ws + O_PMWH);
    float* ap = Hp0;   // Hp0 dead after proj1
    float* aq = Hq0;
    float* Zp = bufX;  // Xp1 dead after rec1
    float* Yq = bufXq; // Xq1 dead after rec1

    prep_kernel<<<688, 256, 0, stream>>>(pre0_Wih, pre0_Whh, pre1_Wih, pre1_Whh,
                                         mq_Wq, mq_Wp, mq_Wh, mq_Whh,
                                         WT0, WT1, WTq, WTp, WTz, mq_Wih,
                                         P0hh, P1hh, PMhh, PMwh);
    proj_kernel<EMB, 512><<<660, 512, 0, stream>>>(passage, WT0, pre0_b, bufX, TP,
                                                   question, WT0, pre0_b, bufXq);
    rec_pre_kernel<<<256, 768, 0, stream>>>(bufX, bufXq, P0hh, mask_p, mask_q, Hp0, Hq0);
    proj_kernel<256, 512><<<660, 512, 0, stream>>>(Hp0, WT1, pre1_b, bufX, TP,
                                                   Hq0, WT1, pre1_b, bufXq);
    rec_pre_kernel<<<256, 768, 0, stream>>>(bufX, bufXq, P1hh, mask_p, mask_q, Hp1, Hq1);
    proj_kernel<256, 256><<<660, 256, 0, stream>>>(Hp1, WTp, mq_bp, ap, TP,
                                                   Hq1, WTq, nullptr, aq);
    proj_kernel<256, 512><<<600, 512, 0, stream>>>(Hp1, WTz, mq_b, Zp, TP,
                                                   nullptr, nullptr, nullptr, nullptr);
    yq_kernel<<<60, 512, 0, stream>>>(Hq1, mq_Wih, Yq);
    match_kernel<<<128, 1024, 0, stream>>>(ap, aq, Zp, Yq, mq_Wa, mask_p,
                                           PMwh, PMhh, (float*)d_out);
}